// Round 1
// 1133.310 us; speedup vs baseline: 1.1891x; 1.1891x over previous
//
#include <hip/hip_runtime.h>

#define DIMX 4096
#define DVX  1024
#define HX   16
#define DHX  64
#define NSX  32
#define BX   8
#define LX   2048
#define EPSF 1e-5f

typedef unsigned short u16;
typedef unsigned int   u32;

using bf16x8 = __attribute__((ext_vector_type(8))) __bf16;
using f32x4  = __attribute__((ext_vector_type(4))) float;

__device__ __forceinline__ float bfu(u16 u) {
    union { u32 i; float f; } c; c.i = ((u32)u) << 16; return c.f;
}
__device__ __forceinline__ u16 f2b(float f) {
    union { float f; u32 u; } c; c.f = f;
    u32 u = c.u;
    u32 r = (u + 0x7fffu + ((u >> 16) & 1u)) >> 16;
    return (u16)r;
}

// async global->LDS DMA, 16B per lane; LDS dest = wave-uniform base + lane*16
__device__ __forceinline__ void async16(const u16* g, u16* l) {
    __builtin_amdgcn_global_load_lds(
        (const __attribute__((address_space(1))) void*)g,
        (__attribute__((address_space(3))) void*)l, 16, 0, 0);
}

// load 8 logical elements (idx multiple of 8, 16B-aligned base) as fp32
template<bool ISF>
__device__ __forceinline__ void ld8(const void* base, size_t idx, float o[8]) {
    if (ISF) {
        const float* f = (const float*)base + idx;
        float4 a = *(const float4*)f, b = *(const float4*)(f + 4);
        o[0]=a.x; o[1]=a.y; o[2]=a.z; o[3]=a.w;
        o[4]=b.x; o[5]=b.y; o[6]=b.z; o[7]=b.w;
    } else {
        const u16* h = (const u16*)base + idx;
        uint4 v = *(const uint4*)h;
        o[0]=bfu(v.x & 0xffff); o[1]=bfu(v.x >> 16);
        o[2]=bfu(v.y & 0xffff); o[3]=bfu(v.y >> 16);
        o[4]=bfu(v.z & 0xffff); o[5]=bfu(v.z >> 16);
        o[6]=bfu(v.w & 0xffff); o[7]=bfu(v.w >> 16);
    }
}
__device__ __forceinline__ float ld1(const void* base, size_t idx, bool isf) {
    return isf ? ((const float*)base)[idx] : bfu(((const u16*)base)[idx]);
}

// ---------------- K0: dtype detector -------------------------------------
__global__ __launch_bounds__(256) void detect_kernel(const u16* __restrict__ X,
                                                     int* __restrict__ flag) {
    __shared__ int cnt;
    if (threadIdx.x == 0) cnt = 0;
    __syncthreads();
    int local = 0;
    for (int i = threadIdx.x; i < 8192; i += 256) {
        u32 e = ((u32)X[i] >> 7) & 0xffu;
        if (e >= 200u) local++;
    }
    atomicAdd(&cnt, local);
    __syncthreads();
    if (threadIdx.x == 0) *flag = (cnt > 32) ? 1 : 0;
}

// ---------------- K0b: fp32 -> bf16 bulk converter -------------------------
// Only active when inputs are fp32 (flag==1). Grid-stride over 8-elem groups.
__global__ __launch_bounds__(256) void cvt_kernel(const int* __restrict__ flag,
                                                  const float* __restrict__ src,
                                                  u16* __restrict__ dst, int ngrp) {
    if (*flag == 0) return;
    int stride = gridDim.x * 256;
    for (int i = blockIdx.x * 256 + threadIdx.x; i < ngrp; i += stride) {
        const float4* f = (const float4*)(src + (size_t)i * 8);
        float4 a = f[0], b = f[1];
        uint4 r;
        r.x = (u32)f2b(a.x) | ((u32)f2b(a.y) << 16);
        r.y = (u32)f2b(a.z) | ((u32)f2b(a.w) << 16);
        r.z = (u32)f2b(b.x) | ((u32)f2b(b.y) << 16);
        r.w = (u32)f2b(b.z) | ((u32)f2b(b.w) << 16);
        *(uint4*)(dst + (size_t)i * 8) = r;
    }
}

// ---------------- K1: Qp = S @ Wq^T + bq  (32 x 1024, fp32 to ws) ----------
template<bool ISF>
__device__ __forceinline__ float dotDV(const void* a, const void* b) {
    float acc = 0.f;
#pragma unroll 4
    for (int j = 0; j < DVX / 8; j++) {
        float x[8], y[8];
        ld8<ISF>(a, (size_t)j * 8, x);
        ld8<ISF>(b, (size_t)j * 8, y);
#pragma unroll
        for (int e = 0; e < 8; e++) acc += x[e] * y[e];
    }
    return acc;
}

__global__ __launch_bounds__(256) void qp_kernel(
        const int* __restrict__ flag, const void* __restrict__ S,
        const void* __restrict__ Wq, const void* __restrict__ bq,
        float* __restrict__ Qp) {
    int idx = blockIdx.x * 256 + threadIdx.x;      // 32768 outputs
    int q = idx >> 10, n = idx & 1023;
    bool isf = (*flag != 0);
    float acc;
    if (isf) acc = dotDV<true>((const float*)S + (size_t)q * DVX,
                               (const float*)Wq + (size_t)n * DVX);
    else     acc = dotDV<false>((const u16*)S + (size_t)q * DVX,
                                (const u16*)Wq + (size_t)n * DVX);
    Qp[idx] = acc + ld1(bq, n, isf);
}

// ---------------- K2: fused K/V projection GEMM (m97 + XCD + LDS swizzle) --
#define TM 128
#define TN 128
#define BKK 32
#define LDT 32

__device__ __forceinline__ uint4 pack8(float o[8]) {
    uint4 r;
    r.x = (u32)f2b(o[0]) | ((u32)f2b(o[1]) << 16);
    r.y = (u32)f2b(o[2]) | ((u32)f2b(o[3]) << 16);
    r.z = (u32)f2b(o[4]) | ((u32)f2b(o[5]) << 16);
    r.w = (u32)f2b(o[6]) | ((u32)f2b(o[7]) << 16);
    return r;
}

// -------- fast path: bf16 inputs (native or pre-converted), DMA staging ----
__global__ __launch_bounds__(256) void kv_gemm2(
        const int* __restrict__ flag,
        const void* __restrict__ X,  const u16* __restrict__ Xb,
        const void* __restrict__ Wk, const void* __restrict__ bk,
        const void* __restrict__ Wv, const void* __restrict__ bv,
        const u16* __restrict__ Wkb, const u16* __restrict__ Wvb,
        u16* __restrict__ Kp, u16* __restrict__ Vp) {
    __shared__ u16 As[TM * LDT];
    __shared__ u16 Bs[TN * LDT];
    const bool isf = (*flag != 0);
    const u16* Xs = isf ? Xb : (const u16*)X;

    const int t = threadIdx.x;
    const int lane = t & 63, w = t >> 6;
    const int wm = w >> 1, wn = w & 1;
    const int quad = lane >> 4, l16 = lane & 15;
    const int bl = blockIdx.x;
    const int xcd = bl & 7, bq = bl >> 3;
    const int m0 = (xcd + 8 * (bq >> 4)) * TM;
    const int n0 = (bq & 15) * TN;
    const u16* Wb16; const void* bias; int boff;
    if (n0 < DVX) { Wb16 = (isf ? Wkb : (const u16*)Wk) + (size_t)n0 * DIMX;
                    bias = bk; boff = n0; }
    else          { Wb16 = (isf ? Wvb : (const u16*)Wv) + (size_t)(n0 - DVX) * DIMX;
                    bias = bv; boff = n0 - DVX; }

    f32x4 acc[4][4];
#pragma unroll
    for (int i = 0; i < 4; i++)
#pragma unroll
        for (int j = 0; j < 4; j++) acc[i][j] = {0.f, 0.f, 0.f, 0.f};

    // LDS chunk swizzle: LDS chunk c of row r holds global chunk c^((r>>1)&3)
    const int srow = lane >> 2;
    const int gcol = ((lane & 3) ^ ((lane >> 3) & 3)) * 8;
    const int ph = (l16 >> 1) & 3;

    for (int k0 = 0; k0 < DIMX; k0 += BKK) {
        __syncthreads();
#pragma unroll
        for (int c = 0; c < 2; c++) {
            int rr = w * 32 + c * 16;
            async16(Xs + (size_t)(m0 + rr + srow) * DIMX + k0 + gcol,
                    As + rr * LDT);
            async16(Wb16 + (size_t)(rr + srow) * DIMX + k0 + gcol,
                    Bs + rr * LDT);
        }
        __syncthreads();
        bf16x8 af[4], bfr[4];
#pragma unroll
        for (int mi = 0; mi < 4; mi++) {
            int ar = wm * 64 + mi * 16 + l16;
            af[mi] = *(const bf16x8*)&As[ar * LDT + (quad ^ ph) * 8];
        }
#pragma unroll
        for (int ni = 0; ni < 4; ni++) {
            int br = wn * 64 + ni * 16 + l16;
            bfr[ni] = *(const bf16x8*)&Bs[br * LDT + (quad ^ ph) * 8];
        }
#pragma unroll
        for (int mi = 0; mi < 4; mi++)
#pragma unroll
            for (int ni = 0; ni < 4; ni++)
                acc[mi][ni] = __builtin_amdgcn_mfma_f32_16x16x32_bf16(
                    af[mi], bfr[ni], acc[mi][ni], 0, 0, 0);
    }

    // D layout (m89-verified): col = lane&15 (n), row = quad*4+reg (m)
#pragma unroll
    for (int mi = 0; mi < 4; mi++) {
#pragma unroll
        for (int ni = 0; ni < 4; ni++) {
            int colL = wn * 64 + ni * 16 + l16;
            int col = n0 + colL;
            float bb = ld1(bias, (size_t)(boff + colL), isf);
            u16* dst; int dcol;
            if (col < DVX) { dst = Kp; dcol = col; }
            else           { dst = Vp; dcol = col - DVX; }
#pragma unroll
            for (int r = 0; r < 4; r++) {
                int row = m0 + wm * 64 + mi * 16 + quad * 4 + r;
                dst[(size_t)row * DVX + dcol] = f2b(acc[mi][ni][r] + bb);
            }
        }
    }
}

// -------- fallback path (small workspace): original dual-dtype body --------
template<bool ISF>
__device__ void kv_body(const void* __restrict__ X,
                        const void* __restrict__ Wk, const void* __restrict__ bk,
                        const void* __restrict__ Wv, const void* __restrict__ bv,
                        u16* __restrict__ Kp, u16* __restrict__ Vp,
                        u16* As, u16* Bs) {
    const int t = threadIdx.x;
    const int lane = t & 63, w = t >> 6;
    const int wm = w >> 1, wn = w & 1;
    const int quad = lane >> 4, l16 = lane & 15;
    const int bl = blockIdx.x;
    const int xcd = bl & 7, bq = bl >> 3;
    const int m0 = (xcd + 8 * (bq >> 4)) * TM;
    const int n0 = (bq & 15) * TN;
    const void* Wbase; const void* bias; int boff;
    size_t woff;
    if (n0 < DVX) { Wbase = Wk; bias = bk; woff = (size_t)n0 * DIMX; boff = n0; }
    else          { Wbase = Wv; bias = bv; woff = (size_t)(n0 - DVX) * DIMX; boff = n0 - DVX; }
    const u16* Wb16 = (const u16*)Wbase + woff;
    const float* Wbf = (const float*)Wbase + woff;

    f32x4 acc[4][4];
#pragma unroll
    for (int i = 0; i < 4; i++)
#pragma unroll
        for (int j = 0; j < 4; j++) acc[i][j] = {0.f, 0.f, 0.f, 0.f};

    const int srow = lane >> 2;
    const int gcol = ((lane & 3) ^ ((lane >> 3) & 3)) * 8;
    const int ph = (l16 >> 1) & 3;
    const int r0 = t >> 2, c0 = (t & 3) * 8;
    const int r1 = r0 + 64;
    const int swc = (((t & 3) ^ ((r0 >> 1) & 3))) * 8;

    for (int k0 = 0; k0 < DIMX; k0 += BKK) {
        if constexpr (ISF) {
            float oa0[8], oa1[8], ob0[8], ob1[8];
            ld8<true>(X,   (size_t)(m0 + r0) * DIMX + k0 + c0, oa0);
            ld8<true>(X,   (size_t)(m0 + r1) * DIMX + k0 + c0, oa1);
            ld8<true>(Wbf, (size_t)r0 * DIMX + k0 + c0, ob0);
            ld8<true>(Wbf, (size_t)r1 * DIMX + k0 + c0, ob1);
            __syncthreads();
            *(uint4*)&As[r0 * LDT + swc] = pack8(oa0);
            *(uint4*)&As[r1 * LDT + swc] = pack8(oa1);
            *(uint4*)&Bs[r0 * LDT + swc] = pack8(ob0);
            *(uint4*)&Bs[r1 * LDT + swc] = pack8(ob1);
        } else {
            __syncthreads();
#pragma unroll
            for (int c = 0; c < 2; c++) {
                int rr = w * 32 + c * 16;
                async16((const u16*)X + (size_t)(m0 + rr + srow) * DIMX + k0 + gcol,
                        As + rr * LDT);
                async16(Wb16 + (size_t)(rr + srow) * DIMX + k0 + gcol,
                        Bs + rr * LDT);
            }
        }
        __syncthreads();
        bf16x8 af[4], bfr[4];
#pragma unroll
        for (int mi = 0; mi < 4; mi++) {
            int ar = wm * 64 + mi * 16 + l16;
            af[mi] = *(const bf16x8*)&As[ar * LDT + (quad ^ ph) * 8];
        }
#pragma unroll
        for (int ni = 0; ni < 4; ni++) {
            int br = wn * 64 + ni * 16 + l16;
            bfr[ni] = *(const bf16x8*)&Bs[br * LDT + (quad ^ ph) * 8];
        }
#pragma unroll
        for (int mi = 0; mi < 4; mi++)
#pragma unroll
            for (int ni = 0; ni < 4; ni++)
                acc[mi][ni] = __builtin_amdgcn_mfma_f32_16x16x32_bf16(
                    af[mi], bfr[ni], acc[mi][ni], 0, 0, 0);
    }

#pragma unroll
    for (int mi = 0; mi < 4; mi++) {
#pragma unroll
        for (int ni = 0; ni < 4; ni++) {
            int colL = wn * 64 + ni * 16 + l16;
            int col = n0 + colL;
            float bb = ld1(bias, (size_t)(boff + colL), ISF);
            u16* dst; int dcol;
            if (col < DVX) { dst = Kp; dcol = col; }
            else           { dst = Vp; dcol = col - DVX; }
#pragma unroll
            for (int r = 0; r < 4; r++) {
                int row = m0 + wm * 64 + mi * 16 + quad * 4 + r;
                dst[(size_t)row * DVX + dcol] = f2b(acc[mi][ni][r] + bb);
            }
        }
    }
}

__global__ __launch_bounds__(256) void kv_gemm(
        const int* __restrict__ flag, const void* __restrict__ X,
        const void* __restrict__ Wk, const void* __restrict__ bk,
        const void* __restrict__ Wv, const void* __restrict__ bv,
        u16* __restrict__ Kp, u16* __restrict__ Vp) {
    __shared__ u16 As[TM * LDT];
    __shared__ u16 Bs[TN * LDT];
    if (*flag) kv_body<true>(X, Wk, bk, Wv, bv, Kp, Vp, As, Bs);
    else       kv_body<false>(X, Wk, bk, Wv, bv, Kp, Vp, As, Bs);
}

// ---------------- K3: attention, one block per (b,h, 4-seed group) ---------
#define QG 4
__global__ __launch_bounds__(256) void attn_kernel(
        const float* __restrict__ Qp, const u16* __restrict__ Kp,
        const u16* __restrict__ Vp, const int* __restrict__ pad,
        float* __restrict__ Oat) {
    __shared__ float qv[QG * DHX];          // 1 KB
    __shared__ float sc[QG * LX];           // 32 KB
    __shared__ float rpart[256 * 8];        // 8 KB
    __shared__ float invs[QG];
    const int blk = blockIdx.x;
    const int nqg = NSX / QG;               // 8
    const int b  = blk / (HX * nqg);
    const int h  = (blk / nqg) % HX;
    const int q0 = (blk % nqg) * QG;
    const int t = threadIdx.x;
    const int w = t >> 6, lane = t & 63;

    qv[t] = Qp[(size_t)(q0 + (t >> 6)) * DVX + h * DHX + (t & 63)];
    __syncthreads();

    const u16* Kb = Kp + (size_t)b * LX * DVX + h * DHX;
    const float4* qf4 = (const float4*)(qv + w * DHX);
    float lmax = -3e38f;
    for (int i = 0; i < LX / 64; i++) {
        int k = i * 64 + lane;
        const uint4* kr = (const uint4*)(Kb + (size_t)k * DVX);
        float s = 0.f;
#pragma unroll
        for (int j8 = 0; j8 < 8; j8++) {
            uint4 v = kr[j8];
            float4 qa = qf4[j8 * 2], qb = qf4[j8 * 2 + 1];
            s += bfu(v.x & 0xffff) * qa.x + bfu(v.x >> 16) * qa.y
               + bfu(v.y & 0xffff) * qa.z + bfu(v.y >> 16) * qa.w
               + bfu(v.z & 0xffff) * qb.x + bfu(v.z >> 16) * qb.y
               + bfu(v.w & 0xffff) * qb.z + bfu(v.w >> 16) * qb.w;
        }
        s *= 0.03125f;
        s = (pad[b * LX + k] != 0) ? s : -1e30f;
        sc[w * LX + k] = s;
        lmax = fmaxf(lmax, s);
    }
#pragma unroll
    for (int off = 32; off > 0; off >>= 1)
        lmax = fmaxf(lmax, __shfl_xor(lmax, off, 64));
    float lsum = 0.f;
    for (int i = 0; i < LX / 64; i++) {
        int k = i * 64 + lane;
        float sv = sc[w * LX + k];
        float e = (sv > -1e29f) ? __expf(sv - lmax) : 0.f;
        sc[w * LX + k] = e;
        lsum += e;
    }
#pragma unroll
    for (int off = 32; off > 0; off >>= 1)
        lsum += __shfl_xor(lsum, off, 64);
    if (lane == 0) invs[w] = (lsum > 0.f) ? 1.f / lsum : 0.f;

    const int kg = (t >> 3) & 7, dg = t & 7;
    const u16* Vb = Vp + (size_t)b * LX * DVX + h * DHX + dg * 8;
    float a8[8];
#pragma unroll
    for (int e = 0; e < 8; e++) a8[e] = 0.f;
    for (int i = 0; i < LX / 8; i++) {
        int k = i * 8 + kg;
        float p = sc[w * LX + k];
        uint4 v = *(const uint4*)(Vb + (size_t)k * DVX);
        a8[0] += p * bfu(v.x & 0xffff); a8[1] += p * bfu(v.x >> 16);
        a8[2] += p * bfu(v.y & 0xffff); a8[3] += p * bfu(v.y >> 16);
        a8[4] += p * bfu(v.z & 0xffff); a8[5] += p * bfu(v.z >> 16);
        a8[6] += p * bfu(v.w & 0xffff); a8[7] += p * bfu(v.w >> 16);
    }
#pragma unroll
    for (int e = 0; e < 8; e++) rpart[t * 8 + e] = a8[e];
    __syncthreads();

    {
        int q = t >> 6, d = t & 63;
        float o = 0.f;
#pragma unroll
        for (int g = 0; g < 8; g++)
            o += rpart[(q * 64 + g * 8 + (d >> 3)) * 8 + (d & 7)];
        o *= invs[q];
        Oat[((size_t)(b * NSX + q0 + q)) * DVX + h * DHX + d] = o;
    }
}

// ---------------- K4: residual + LN0 + MLP(relu) residual + LN1 ------------
template<bool ISF>
__device__ void epi_body(float* u, float* y0, float* red,
                         const float* __restrict__ Oat, const void* __restrict__ S,
                         const void* __restrict__ Wo, const void* __restrict__ bo,
                         const void* __restrict__ g0, const void* __restrict__ be0,
                         const void* __restrict__ g1, const void* __restrict__ be1,
                         void* __restrict__ out) {
    const int bq = blockIdx.x;            // (b*32+q)
    const int q = bq & 31;
    const int t = threadIdx.x;
    const int w = t >> 6, lane = t & 63;

    float ls = 0.f, ls2 = 0.f;
#pragma unroll
    for (int j = 0; j < 2; j++) {
        int c = t + 512 * j;
        float v = ld1(S, (size_t)q * DVX + c, ISF) + Oat[(size_t)bq * DVX + c];
        u[c] = v; ls += v; ls2 += v * v;
    }
    red[t] = ls; __syncthreads();
    for (int s2 = 256; s2 > 0; s2 >>= 1) { if (t < s2) red[t] += red[t + s2]; __syncthreads(); }
    float mu = red[0] / DVX; __syncthreads();
    red[t] = ls2; __syncthreads();
    for (int s2 = 256; s2 > 0; s2 >>= 1) { if (t < s2) red[t] += red[t + s2]; __syncthreads(); }
    float var = red[0] / DVX - mu * mu;
    float r = rsqrtf(var + EPSF);
    __syncthreads();
#pragma unroll
    for (int j = 0; j < 2; j++) {
        int c = t + 512 * j;
        y0[c] = (u[c] - mu) * r * ld1(g0, c, ISF) + ld1(be0, c, ISF);
    }
    __syncthreads();

    // GEMV: 8 waves x 128 iters = 1024 outputs
    for (int i = 0; i < 128; i++) {
        int n = i * 8 + w;
        float p = 0.f;
        if constexpr (ISF) {
            float wv[8];
            const float* row = (const float*)Wo + (size_t)n * DVX;
            ld8<true>(row, lane * 16, wv);
#pragma unroll
            for (int e = 0; e < 8; e++) p += wv[e] * y0[lane * 16 + e];
            ld8<true>(row, lane * 16 + 8, wv);
#pragma unroll
            for (int e = 0; e < 8; e++) p += wv[e] * y0[lane * 16 + 8 + e];
        } else {
            const uint4* row = (const uint4*)((const u16*)Wo + (size_t)n * DVX);
            uint4 v0 = row[lane], v1 = row[lane + 64];
            const float* ya = y0 + lane * 8;
            const float* yb = y0 + 512 + lane * 8;
            p += bfu(v0.x & 0xffff) * ya[0] + bfu(v0.x >> 16) * ya[1]
               + bfu(v0.y & 0xffff) * ya[2] + bfu(v0.y >> 16) * ya[3]
               + bfu(v0.z & 0xffff) * ya[4] + bfu(v0.z >> 16) * ya[5]
               + bfu(v0.w & 0xffff) * ya[6] + bfu(v0.w >> 16) * ya[7];
            p += bfu(v1.x & 0xffff) * yb[0] + bfu(v1.x >> 16) * yb[1]
               + bfu(v1.y & 0xffff) * yb[2] + bfu(v1.y >> 16) * yb[3]
               + bfu(v1.z & 0xffff) * yb[4] + bfu(v1.z >> 16) * yb[5]
               + bfu(v1.w & 0xffff) * yb[6] + bfu(v1.w >> 16) * yb[7];
        }
#pragma unroll
        for (int off = 32; off > 0; off >>= 1)
            p += __shfl_xor(p, off, 64);
        if (lane == 0) {
            float z = p + ld1(bo, n, ISF);
            u[n] = y0[n] + fmaxf(z, 0.f);     // reuse u as y1
        }
    }
    __syncthreads();
    ls = 0.f; ls2 = 0.f;
#pragma unroll
    for (int j = 0; j < 2; j++) {
        int c = t + 512 * j; float v = u[c]; ls += v; ls2 += v * v;
    }
    red[t] = ls; __syncthreads();
    for (int s2 = 256; s2 > 0; s2 >>= 1) { if (t < s2) red[t] += red[t + s2]; __syncthreads(); }
    mu = red[0] / DVX; __syncthreads();
    red[t] = ls2; __syncthreads();
    for (int s2 = 256; s2 > 0; s2 >>= 1) { if (t < s2) red[t] += red[t + s2]; __syncthreads(); }
    var = red[0] / DVX - mu * mu;
    r = rsqrtf(var + EPSF);
#pragma unroll
    for (int j = 0; j < 2; j++) {
        int c = t + 512 * j;
        float v = (u[c] - mu) * r * ld1(g1, c, ISF) + ld1(be1, c, ISF);
        if (ISF) ((float*)out)[(size_t)bq * DVX + c] = v;
        else     ((u16*)out)[(size_t)bq * DVX + c] = f2b(v);
    }
}

__global__ __launch_bounds__(512) void epi_kernel(
        const int* __restrict__ flag,
        const float* __restrict__ Oat, const void* __restrict__ S,
        const void* __restrict__ Wo, const void* __restrict__ bo,
        const void* __restrict__ g0, const void* __restrict__ be0,
        const void* __restrict__ g1, const void* __restrict__ be1,
        void* __restrict__ out) {
    __shared__ float u[DVX];
    __shared__ float y0[DVX];
    __shared__ float red[512];
    if (*flag) epi_body<true>(u, y0, red, Oat, S, Wo, bo, g0, be0, g1, be1, out);
    else       epi_body<false>(u, y0, red, Oat, S, Wo, bo, g0, be0, g1, be1, out);
}

extern "C" void kernel_launch(void* const* d_in, const int* in_sizes, int n_in,
                              void* d_out, int out_size, void* d_ws, size_t ws_size,
                              hipStream_t stream) {
    (void)in_sizes; (void)n_in; (void)out_size;
    const void* X    = d_in[0];
    const int* pad   = (const int*)d_in[1];
    const void* S    = d_in[2];
    const void* Wq   = d_in[3];
    const void* bq   = d_in[4];
    const void* Wk   = d_in[5];
    const void* bk   = d_in[6];
    const void* Wv   = d_in[7];
    const void* bv   = d_in[8];
    const void* Wo   = d_in[9];
    const void* bo   = d_in[10];
    const void* g0   = d_in[11];
    const void* be0  = d_in[12];
    const void* g1   = d_in[13];
    const void* be1  = d_in[14];

    char* ws = (char*)d_ws;
    int*   flag = (int*)ws;                                // 256 B reserved
    float* Qp  = (float*)(ws + 256);                       // 128 KiB
    float* Oat = (float*)(ws + 256 + 131072);              // 1 MiB
    u16*   Kp  = (u16*)(ws + 256 + 131072 + 1048576);      // 32 MiB
    u16*   Vp  = Kp + (size_t)BX * LX * DVX;               // 32 MiB
    u16*   Xb  = Vp + (size_t)BX * LX * DVX;               // 128 MiB (bf16 X)
    u16*   Wkb = Xb + (size_t)BX * LX * DIMX;              // 8 MiB
    u16*   Wvb = Wkb + (size_t)DVX * DIMX;                 // 8 MiB

    size_t need = 256 + 131072 + 1048576
                + 2 * (size_t)BX * LX * DVX * 2
                + (size_t)BX * LX * DIMX * 2
                + 2 * (size_t)DVX * DIMX * 2;              // ~209 MiB

    detect_kernel<<<1, 256, 0, stream>>>((const u16*)X, flag);
    qp_kernel<<<128, 256, 0, stream>>>(flag, S, Wq, bq, Qp);

    if (ws_size >= need) {
        // one-shot fp32->bf16 conversion (no-op if input already bf16),
        // then the DMA-staged bf16 GEMM (m97 structure, ~2.3x the fp32 path)
        cvt_kernel<<<2048, 256, 0, stream>>>(flag, (const float*)X, Xb,
                                             BX * LX * DIMX / 8);
        cvt_kernel<<<512, 256, 0, stream>>>(flag, (const float*)Wk, Wkb,
                                            DVX * DIMX / 8);
        cvt_kernel<<<512, 256, 0, stream>>>(flag, (const float*)Wv, Wvb,
                                            DVX * DIMX / 8);
        kv_gemm2<<<2048, 256, 0, stream>>>(flag, X, Xb, Wk, bk, Wv, bv,
                                           Wkb, Wvb, Kp, Vp);
    } else {
        kv_gemm<<<2048, 256, 0, stream>>>(flag, X, Wk, bk, Wv, bv, Kp, Vp);
    }

    attn_kernel<<<BX * HX * (NSX / QG), 256, 0, stream>>>(Qp, Kp, Vp, pad, Oat);
    epi_kernel<<<BX * NSX, 512, 0, stream>>>(flag, Oat, S, Wo, bo, g0, be0, g1, be1, (void*)d_out);
}